// Round 1
// baseline (150.024 us; speedup 1.0000x reference)
//
#include <hip/hip_runtime.h>
#include <math.h>

// PhysicsConstraintLayer: per 10x10 block water-filling (simplex projection)
// q = clip(p - theta, 0) with theta s.t. sum(q) = S (block sum of inp_lin).
// Michelot's finite algorithm instead of sort+cumsum: identical theta.
//
// Shapes (fixed by setup_inputs): [4,1,12,800,800] f32, scale=10.
// 48 images of 800x800, 80x80 blocks of 10x10 = 307200 blocks.
// One 64-lane wave per block; lane l holds elements l and l+64 (if <100).

constexpr float kNorm    = 11.0f;
constexpr float kInvNorm = 1.0f / 11.0f;

__global__ __launch_bounds__(256) void pcl_waterfill_kernel(
    const float* __restrict__ pred,
    const float* __restrict__ inp,
    float* __restrict__ out,
    int n_images)
{
    const int tid  = blockIdx.x * 256 + threadIdx.x;
    const int wid  = tid >> 6;   // global wave id == block id
    const int lane = tid & 63;

    const int img = wid / 6400;           // 80*80 blocks per image
    if (img >= n_images) return;
    const int rem = wid - img * 6400;
    const int by  = rem / 80;
    const int bx  = rem - by * 80;

    const int e0 = lane;                  // element 0..63
    const int e1 = lane + 64;             // element 64..127 (valid < 100)
    const bool has1 = (e1 < 100);

    const int r0 = e0 / 10, c0 = e0 - r0 * 10;
    const int r1 = e1 / 10, c1 = e1 - r1 * 10;

    const long long ibase = (long long)img * 640000LL;
    const int rowBase = by * 10, colBase = bx * 10;
    const long long a0 = ibase + (long long)(rowBase + r0) * 800 + (colBase + c0);
    const long long a1 = ibase + (long long)(rowBase + r1) * 800 + (colBase + c1);

    // to linear domain: clip(expm1(11x), 0) via fast exp (abs err ~1e-6 rel)
    float p0, p1, s0, s1;
    {
        const float xp = pred[a0];
        const float xi = inp[a0];
        p0 = fmaxf(__expf(xp * kNorm) - 1.0f, 0.0f);
        s0 = fmaxf(__expf(xi * kNorm) - 1.0f, 0.0f);
    }
    if (has1) {
        const float xp = pred[a1];
        const float xi = inp[a1];
        p1 = fmaxf(__expf(xp * kNorm) - 1.0f, 0.0f);
        s1 = fmaxf(__expf(xi * kNorm) - 1.0f, 0.0f);
    } else {
        p1 = -INFINITY;  // never enters active set (p1 > theta always false)
        s1 = 0.0f;
    }

    // wave-wide S (target sum) and sum(p)
    float S    = s0 + s1;
    float sumP = p0 + fmaxf(p1, 0.0f);   // -inf sentinel contributes 0
    #pragma unroll
    for (int off = 32; off; off >>= 1) {
        S    += __shfl_xor(S, off);
        sumP += __shfl_xor(sumP, off);
    }

    // Michelot: theta_0 from full set (n=100); shrink active set until stable.
    float theta = (sumP - S) * 0.01f;
    int prev = 100;
    #pragma unroll 1
    for (int it = 0; it < 100; ++it) {
        float sm = (p0 > theta) ? p0 : 0.0f;
        float fc = (p0 > theta) ? 1.0f : 0.0f;
        if (p1 > theta) { sm += p1; fc += 1.0f; }
        #pragma unroll
        for (int off = 32; off; off >>= 1) {
            sm += __shfl_xor(sm, off);
            fc += __shfl_xor(fc, off);
        }
        const int cnt = (int)fc;
        if (cnt == prev || cnt == 0) break;  // active set stable (or S==0 edge)
        theta = (sm - S) / fc;
        prev = cnt;
    }

    // q = clip(p - theta, 0); out = log1p(q)/11 via fast log
    const float q0 = fmaxf(p0 - theta, 0.0f);
    out[a0] = __logf(1.0f + q0) * kInvNorm;
    if (has1) {
        const float q1 = fmaxf(p1 - theta, 0.0f);
        out[a1] = __logf(1.0f + q1) * kInvNorm;
    }
}

extern "C" void kernel_launch(void* const* d_in, const int* in_sizes, int n_in,
                              void* d_out, int out_size, void* d_ws, size_t ws_size,
                              hipStream_t stream) {
    const float* pred = (const float*)d_in[0];
    const float* inp  = (const float*)d_in[1];
    float* out        = (float*)d_out;

    const int n_images = in_sizes[0] / (800 * 800);  // 48
    const int waves    = n_images * 6400;            // one wave per 10x10 block
    const int blocks   = (waves + 3) / 4;            // 4 waves per 256-thr WG

    pcl_waterfill_kernel<<<blocks, 256, 0, stream>>>(pred, inp, out, n_images);
}

// Round 2
// 94.460 us; speedup vs baseline: 1.5882x; 1.5882x over previous
//
#include <hip/hip_runtime.h>
#include <math.h>

// PhysicsConstraintLayer: per 10x10 block water-filling (simplex projection).
// q = clip(p - theta, 0) with theta s.t. sum(q) = S (block sum of inp_lin).
// Michelot's finite algorithm (active-set shrink) == reference sort+cumsum theta.
//
// R2 structure: TWO blocks per 64-lane wave (one per 32-lane half).
// Lane l (l32 = l&31) holds elements {l32, l32+32, l32+64, l32+96} of its
// half's block (slot 3 valid only for l32<4; 100 elements total).
// Float reductions: 5-step __shfl_xor butterfly within the half.
// Active-set COUNT: __ballot + scalar popcount per half (SALU, free).

constexpr float kNorm    = 11.0f;
constexpr float kInvNorm = 1.0f / 11.0f;

__global__ __launch_bounds__(256) void pcl_waterfill2_kernel(
    const float* __restrict__ pred,
    const float* __restrict__ inp,
    float* __restrict__ out,
    int n_blocks_total)
{
    const int tid  = blockIdx.x * 256 + threadIdx.x;
    const int wid  = tid >> 6;
    const int lane = tid & 63;
    const int half = lane >> 5;
    const int l32  = lane & 31;

    const int blk = wid * 2 + half;       // this half's 10x10 block id
    if (blk >= n_blocks_total) return;

    const int img = blk / 6400;           // 80*80 blocks per 800x800 image
    const int rem = blk - img * 6400;
    const int by  = rem / 80;
    const int bx  = rem - by * 80;

    const float* predI = pred + (long long)img * 640000LL;
    const float* inpI  = inp  + (long long)img * 640000LL;
    float*       outI  = out  + (long long)img * 640000LL;

    const int rowBase = by * 10;
    const int colBase = bx * 10;

    // Load 4 slots, convert to linear domain, accumulate local sums.
    float p[4];
    int   addr[4];
    float sloc = 0.0f;   // local sum of inp_lin (target S contribution)
    float ploc = 0.0f;   // local sum of pred_lin
    #pragma unroll
    for (int k = 0; k < 4; ++k) {
        const int e = l32 + 32 * k;
        if (e < 100) {
            const int r = e / 10;
            const int c = e - r * 10;
            const int a = (rowBase + r) * 800 + colBase + c;
            addr[k] = a;
            const float xp = predI[a];
            const float xi = inpI[a];
            const float pl = fmaxf(__expf(xp * kNorm) - 1.0f, 0.0f);
            const float sl = fmaxf(__expf(xi * kNorm) - 1.0f, 0.0f);
            p[k] = pl;
            ploc += pl;
            sloc += sl;
        } else {
            addr[k] = -1;
            p[k] = -INFINITY;   // sentinel: never enters active set
        }
    }

    // Per-half (32-lane) reduction of S and sum(p): 5 butterfly steps.
    float S = sloc, sumP = ploc;
    #pragma unroll
    for (int off = 16; off; off >>= 1) {
        S    += __shfl_xor(S, off);
        sumP += __shfl_xor(sumP, off);
    }

    // Michelot: theta_0 from full active set (n=100); shrink until stable.
    float theta = (sumP - S) * 0.01f;
    float prevc = 100.0f;
    #pragma unroll 1
    for (int it = 0; it < 100; ++it) {
        float sm = 0.0f;
        unsigned long long bm0, bm1, bm2, bm3;
        {
            const bool a0 = (p[0] > theta); bm0 = __ballot(a0); if (a0) sm += p[0];
            const bool a1 = (p[1] > theta); bm1 = __ballot(a1); if (a1) sm += p[1];
            const bool a2 = (p[2] > theta); bm2 = __ballot(a2); if (a2) sm += p[2];
            const bool a3 = (p[3] > theta); bm3 = __ballot(a3); if (a3) sm += p[3];
        }
        #pragma unroll
        for (int off = 16; off; off >>= 1) sm += __shfl_xor(sm, off);

        // element counts per half via scalar popcounts (SALU)
        const int cl = __popcll(bm0 & 0xffffffffull) + __popcll(bm1 & 0xffffffffull)
                     + __popcll(bm2 & 0xffffffffull) + __popcll(bm3 & 0xffffffffull);
        const int ch = __popcll(bm0 >> 32) + __popcll(bm1 >> 32)
                     + __popcll(bm2 >> 32) + __popcll(bm3 >> 32);
        const float fc = (half == 0) ? (float)cl : (float)ch;

        const bool stable = (fc == prevc) || (fc == 0.0f);
        if (!stable) theta = __fdividef(sm - S, fc);
        prevc = fc;
        if (__all(stable)) break;
    }

    // q = clip(p - theta, 0); out = log1p(q)/11
    #pragma unroll
    for (int k = 0; k < 4; ++k) {
        if (addr[k] >= 0) {
            const float q = fmaxf(p[k] - theta, 0.0f);
            outI[addr[k]] = __logf(1.0f + q) * kInvNorm;
        }
    }
}

extern "C" void kernel_launch(void* const* d_in, const int* in_sizes, int n_in,
                              void* d_out, int out_size, void* d_ws, size_t ws_size,
                              hipStream_t stream) {
    const float* pred = (const float*)d_in[0];
    const float* inp  = (const float*)d_in[1];
    float* out        = (float*)d_out;

    const int n_images = in_sizes[0] / (800 * 800);   // 48
    const int n_blocks = n_images * 6400;             // 307200
    const int waves    = (n_blocks + 1) / 2;          // 2 blocks per wave
    const int wgs      = (waves + 3) / 4;             // 4 waves per 256-thr WG

    pcl_waterfill2_kernel<<<wgs, 256, 0, stream>>>(pred, inp, out, n_blocks);
}